// Round 25
// baseline (161.128 us; speedup 1.0000x reference)
//
#include <hip/hip_runtime.h>
#include <hip/hip_bf16.h>
#include <stdint.h>

// Problem constants: B=2, S=2048, D_MODEL=1024, H=16, Dk=64. M = B*S = 4096.
typedef unsigned short u16;
typedef __attribute__((ext_vector_type(8))) short short8;
typedef __attribute__((ext_vector_type(8))) __bf16 bf16x8;
typedef __attribute__((ext_vector_type(4))) float f32x4;
typedef __attribute__((ext_vector_type(4))) uint32_t u32x4;

#if defined(__has_builtin)
#if __has_builtin(__builtin_amdgcn_global_load_lds)
#define USE_GLLDS 1
#endif
#endif

// Fast 2^x: v_exp_f32 is the native HW op. (__exp2f collides with glibc.)
#if defined(__has_builtin)
#if __has_builtin(__builtin_amdgcn_exp2f)
#define HAVE_EXP2_BUILTIN 1
#endif
#endif
__device__ __forceinline__ float fexp2(float x) {
#ifdef HAVE_EXP2_BUILTIN
  return __builtin_amdgcn_exp2f(x);
#else
  return exp2f(x);
#endif
}

__device__ __forceinline__ u16 f2bf(float f) {
  __hip_bfloat16 h = __float2bfloat16(f);
  return __builtin_bit_cast(u16, h);
}

// Pack 2 fp32 -> 1 u32 of 2 bf16 (RNE) in ONE instruction (T12 recipe).
__device__ __forceinline__ uint32_t cvt_pk_bf16(float lo, float hi) {
  uint32_t w;
  asm("v_cvt_pk_bf16_f32 %0, %1, %2" : "=v"(w) : "v"(lo), "v"(hi));
  return w;
}

__device__ __forceinline__ f32x4 mfma16(bf16x8 a, bf16x8 b, f32x4 c) {
  return __builtin_amdgcn_mfma_f32_16x16x32_bf16(a, b, c, 0, 0, 0);
}

#ifdef USE_GLLDS
__device__ __forceinline__ void async_cp16(const void* g, void* l) {
  __builtin_amdgcn_global_load_lds(
      (const __attribute__((address_space(1))) void*)g,
      (__attribute__((address_space(3))) void*)l, 16, 0, 0);
}
#endif

// Shared epilogue for all GEMM variants. Modes:
//   0: Q  -> bf16 split-head [B,H,S,64], scaled by 0.125*log2(e)  (exp2 dom.)
//   1: K  -> bf16 split-head [B,H,S,64]
//   2: V  -> bf16 TRANSPOSED split-head [B,H,64,S]  (V^T for the PV mfma)
//   3: fp32 row-major [4096,1024] (output projection)
__device__ __forceinline__ void gemm_store(float val, int gm, int gn, int mode,
                                           void* __restrict__ outp) {
  const int b = gm >> 11, s = gm & 2047, h = gn >> 6, d = gn & 63;
  if (mode == 3) {
    ((float*)outp)[(size_t)gm * 1024 + gn] = val;
  } else if (mode == 2) {
    ((u16*)outp)[(((size_t)((b * 16 + h) * 64 + d)) << 11) + s] = f2bf(val);
  } else {
    if (mode == 0) val *= 0.18033688f;  // (1/8)*log2(e): exp2-domain
    ((u16*)outp)[(((size_t)((b * 16 + h) * 2048 + s)) << 6) + d] = f2bf(val);
  }
}

// ---------------------------------------------------------------------------
// Kernel 1: fp32 -> bf16 conversion of q,k,v (4M each) and w_q,w_k,w_v,w_o (1M
// each) into one contiguous 16M-element bf16 region at the start of d_ws.
// ---------------------------------------------------------------------------
__global__ __launch_bounds__(256) void cvt_all(
    const float* __restrict__ q, const float* __restrict__ k,
    const float* __restrict__ v, const float* __restrict__ w0,
    const float* __restrict__ w1, const float* __restrict__ w2,
    const float* __restrict__ w3, u16* __restrict__ dst) {
  size_t i = ((size_t)blockIdx.x * 256 + threadIdx.x) * 8;
  const size_t M1 = 1u << 20;
  const float* s;
  size_t base;
  if (i < 4 * M1) { s = q; base = 0; }
  else if (i < 8 * M1) { s = k; base = 4 * M1; }
  else if (i < 12 * M1) { s = v; base = 8 * M1; }
  else if (i < 13 * M1) { s = w0; base = 12 * M1; }
  else if (i < 14 * M1) { s = w1; base = 13 * M1; }
  else if (i < 15 * M1) { s = w2; base = 14 * M1; }
  else { s = w3; base = 15 * M1; }
  const float4 a = *(const float4*)(s + (i - base));
  const float4 b = *(const float4*)(s + (i - base) + 4);
  short8 r;
  r[0] = (short)f2bf(a.x); r[1] = (short)f2bf(a.y);
  r[2] = (short)f2bf(a.z); r[3] = (short)f2bf(a.w);
  r[4] = (short)f2bf(b.x); r[5] = (short)f2bf(b.y);
  r[6] = (short)f2bf(b.z); r[7] = (short)f2bf(b.w);
  *(short8*)(dst + i) = r;
}

// ---------------------------------------------------------------------------
// GEMM core v7 (m97-exact geometry + T2 swizzle): 4 waves (256 thr), 128x128
// tile, BK=64, single 32KB LDS, GLLDS staging. Wave grid 2x2, wave tile
// 64x64, acc 4x4.
// ---------------------------------------------------------------------------
__device__ __forceinline__ void gemm_core4(const u16* __restrict__ X,
                                           const u16* __restrict__ W,
                                           const float* __restrict__ bias,
                                           void* __restrict__ outp, int mode,
                                           int m0, int n0) {
  __shared__ u16 Al[128 * 64];
  __shared__ u16 Bl[128 * 64];
  const int tid = threadIdx.x;
  const int wv = tid >> 6, l = tid & 63;
  const int wr = wv >> 1, wc = wv & 1;       // wave tile: rows wr*64, cols wc*64
  const int lrow = l & 15, g = l >> 4;
  const int rswe = (lrow & 7) << 3;          // read swizzle (u16 elements)

  f32x4 acc[4][4];
#pragma unroll
  for (int i = 0; i < 4; ++i)
#pragma unroll
    for (int j = 0; j < 4; ++j) acc[i][j] = (f32x4){0.f, 0.f, 0.f, 0.f};

  const int srow = l >> 3;                   // 0..7 (== row&7 for all p)
  const int ccol = l & 7;                    // linear 16B chunk (LDS dest)
  const int gchunk = ccol ^ srow;            // inverse-swizzled source chunk
  const u16* Asrc = X + (size_t)(m0 + wv * 8 + srow) * 1024 + gchunk * 8;
  const u16* Bsrc = W + (size_t)(wv * 8 + srow) * 1024 + gchunk * 8;

  for (int kt = 0; kt < 1024; kt += 64) {
#ifdef USE_GLLDS
#pragma unroll
    for (int p = 0; p < 4; ++p) {
      async_cp16(Asrc + (size_t)p * 32 * 1024 + kt, &Al[p * 2048 + wv * 512]);
      async_cp16(Bsrc + (size_t)p * 32 * 1024 + kt, &Bl[p * 2048 + wv * 512]);
    }
#else
    short8 ar[4], br[4];
#pragma unroll
    for (int p = 0; p < 4; ++p) {
      ar[p] = *(const short8*)(Asrc + (size_t)p * 32 * 1024 + kt);
      br[p] = *(const short8*)(Bsrc + (size_t)p * 32 * 1024 + kt);
    }
#pragma unroll
    for (int p = 0; p < 4; ++p) {
      *(short8*)&Al[(p * 32 + wv * 8 + srow) * 64 + ccol * 8] = ar[p];
      *(short8*)&Bl[(p * 32 + wv * 8 + srow) * 64 + ccol * 8] = br[p];
    }
#endif
    __syncthreads();   // drains staging
#pragma unroll
    for (int ks = 0; ks < 2; ++ks) {
      bf16x8 af[4], bf[4];
      const int qoff = (((ks * 4 + g) << 3) ^ rswe);  // swizzled quad offset
#pragma unroll
      for (int mf = 0; mf < 4; ++mf)
        af[mf] = *(const bf16x8*)&Al[(wr * 64 + mf * 16 + lrow) * 64 + qoff];
#pragma unroll
      for (int nf = 0; nf < 4; ++nf)
        bf[nf] = *(const bf16x8*)&Bl[(wc * 64 + nf * 16 + lrow) * 64 + qoff];
#pragma unroll
      for (int mf = 0; mf < 4; ++mf)
#pragma unroll
        for (int nf = 0; nf < 4; ++nf)
          acc[mf][nf] = mfma16(af[mf], bf[nf], acc[mf][nf]);
    }
    __syncthreads();   // protect buffer before next stage overwrites
  }

  const int rb = (l >> 4) * 4;
#pragma unroll
  for (int mf = 0; mf < 4; ++mf)
#pragma unroll
    for (int nf = 0; nf < 4; ++nf) {
      const int gn = n0 + wc * 64 + nf * 16 + lrow;
      const float bi = bias[gn];
#pragma unroll
      for (int r = 0; r < 4; ++r) {
        const int gm = m0 + wr * 64 + mf * 16 + rb + r;
        gemm_store(acc[mf][nf][r] + bi, gm, gn, mode, outp);
      }
    }
}

// 8-wave BN=64 core (round-18 proven) -- kept for gemm_out.
__device__ __forceinline__ void gemm_core8_64(const u16* __restrict__ X,
                                              const u16* __restrict__ W,
                                              const float* __restrict__ bias,
                                              void* __restrict__ outp,
                                              int mode, int m0, int n0) {
  __shared__ u16 Al[128 * 64];
  __shared__ u16 Bl[64 * 64];
  const int tid = threadIdx.x;
  const int wv = tid >> 6, l = tid & 63;
  const int wr = wv >> 2, wc = wv & 3;       // wave: rows wr*64, cols wc*16
  const int lrow = l & 15, g = l >> 4;
  const int rswe = (lrow & 7) << 3;

  f32x4 acc[4];
#pragma unroll
  for (int i = 0; i < 4; ++i) acc[i] = (f32x4){0.f, 0.f, 0.f, 0.f};

  const int srow = l >> 3;
  const int ccol = l & 7;
  const int gchunk = ccol ^ srow;
  const int arow = wv * 8 + srow;
  const u16* Asrc = X + (size_t)(m0 + arow) * 1024 + gchunk * 8;
  const u16* Bsrc = W + (size_t)arow * 1024 + gchunk * 8;

  for (int kt = 0; kt < 1024; kt += 64) {
#ifdef USE_GLLDS
    async_cp16(Asrc + kt, &Al[(wv * 8) * 64]);
    async_cp16(Asrc + (size_t)64 * 1024 + kt, &Al[(wv * 8 + 64) * 64]);
    async_cp16(Bsrc + kt, &Bl[(wv * 8) * 64]);
#else
    short8 a0 = *(const short8*)(Asrc + kt);
    short8 a1 = *(const short8*)(Asrc + (size_t)64 * 1024 + kt);
    short8 b0 = *(const short8*)(Bsrc + kt);
    *(short8*)&Al[arow * 64 + ccol * 8] = a0;
    *(short8*)&Al[(arow + 64) * 64 + ccol * 8] = a1;
    *(short8*)&Bl[arow * 64 + ccol * 8] = b0;
#endif
    __syncthreads();
#pragma unroll
    for (int ks = 0; ks < 2; ++ks) {
      bf16x8 af[4], bf;
      const int qoff = (((ks * 4 + g) << 3) ^ rswe);
#pragma unroll
      for (int mf = 0; mf < 4; ++mf)
        af[mf] = *(const bf16x8*)&Al[(wr * 64 + mf * 16 + lrow) * 64 + qoff];
      bf = *(const bf16x8*)&Bl[(wc * 16 + lrow) * 64 + qoff];
#pragma unroll
      for (int mf = 0; mf < 4; ++mf) acc[mf] = mfma16(af[mf], bf, acc[mf]);
    }
    __syncthreads();
  }

  const int rb = (l >> 4) * 4;
#pragma unroll
  for (int mf = 0; mf < 4; ++mf) {
    const int gn = n0 + wc * 16 + lrow;
    const float bi = bias[gn];
#pragma unroll
    for (int r = 0; r < 4; ++r) {
      const int gm = m0 + wr * 64 + mf * 16 + rb + r;
      gemm_store(acc[mf][r] + bi, gm, gn, mode, outp);
    }
  }
}

// gemm_proj: 4-wave m97-shape core. Fused grid over concatenated-N (N=3072).
// 768 blocks; XCD-chunk swizzle: chunk = 96 blocks (12 nx x 8 my).
// launch_bounds(256,5): VGPR cap 102 >= measured 96 for this register shape
// (round 2); LDS 32KB x 5 = 160KB = the CU limit -> 5 blocks/CU = 20 waves/CU
// (+25% TLP vs (256,4); round-9 counters showed proj latency-bound).
__global__ __launch_bounds__(256, 5) void gemm_proj(
    const u16* __restrict__ qb, const u16* __restrict__ wqb,
    const float* __restrict__ b_q, const float* __restrict__ b_k,
    const float* __restrict__ b_v, u16* __restrict__ Qh) {
  const int s = blockIdx.x;
  const int xcd = s & 7, c = s >> 3;              // c in [0,96)
  const int nx = (xcd >> 2) * 12 + (c % 12);      // [0,24)
  const int my = (xcd & 3) * 8 + (c / 12);        // [0,32)
  const int z = nx >> 3, nxl = nx & 7;
  const float* bias = (z == 0) ? b_q : ((z == 1) ? b_k : b_v);
  gemm_core4(qb + ((size_t)z << 22), wqb + ((size_t)nx << 17), bias,
             Qh + ((size_t)z << 22), z, my * 128, nxl * 128);
}

// gemm_out: BN=64 tile -> 512 blocks (2 blocks/CU). Chunk = 64 (8 nx x 8 my).
__global__ __launch_bounds__(512, 6) void gemm_out(
    const u16* __restrict__ X, const u16* __restrict__ W,
    const float* __restrict__ bias, float* __restrict__ out) {
  const int s = blockIdx.x;
  const int xcd = s & 7, c = s >> 3;              // c in [0,64)
  const int nx = (xcd >> 2) * 8 + (c & 7);        // [0,16)
  const int my = (xcd & 3) * 8 + (c >> 3);        // [0,32)
  gemm_core8_64(X, W + ((size_t)nx << 16), bias, out, 3, my * 128, nx * 64);
}

// ---------------------------------------------------------------------------
// Flash attention v7 EXACT (best measured: 57.4-58.5us, rounds 13/14/20/21/24).
// v5 sync structure (2 barriers per staging slot, T14 issue-early/write-late),
// KVBLK=128, XOR-swizzled K/V, split-KV(2), separate Pl slab, NO setprio.
// ---------------------------------------------------------------------------
__global__ __launch_bounds__(512, 4) void flash_attn7(
    const u16* __restrict__ Qh, const u16* __restrict__ Kh,
    const u16* __restrict__ VT, u16* __restrict__ Op,
    float2* __restrict__ ml) {
  __shared__ __align__(16) u16 Kbuf[2][4096];    // halves 0,1 of 128-col group
  __shared__ __align__(16) u16 Vbuf[2][4096];
  __shared__ __align__(16) uint32_t Pl[8 * 576]; // per-wave 16 rows x 36 dw

  const int tid = threadIdx.x;
  const int wv = tid >> 6, l = tid & 63;
  const int q = l & 15, g = l >> 4;

  // XCD swizzle: dispatch slot s -> original block o = (s%8)*128 + s/8.
  const int s_lin = blockIdx.x + (blockIdx.y << 4) + (blockIdx.z << 9);
  const int o = ((s_lin & 7) << 7) + (s_lin >> 3);
  const int qt = o & 15, bh = (o >> 4) & 31, z = o >> 9;

  const u16* Qp = Qh + ((size_t)bh * 2048 + qt * 128 + wv * 16) * 64;
  const u16* Kp = Kh + (size_t)bh * 2048 * 64;
  const u16* Vp = VT + (size_t)bh * 64 * 2048;

  // Q fragments (B-operand): lane holds Q[q=l&15][d = ks*32 + g*8 .. +7]
  bf16x8 qf[2];
  qf[0] = *(const bf16x8*)(Qp + q * 64 + g * 8);
  qf[1] = *(const bf16x8*)(Qp + q * 64 + 32 + g * 8);

  f32x4 o_acc[4];
#pragma unroll
  for (int df = 0; df < 4; ++df) o_acc[df] = (f32x4){0.f, 0.f, 0.f, 0.f};
  float m = -1e30f, ls = 0.f;

  const int srow = l >> 3;                       // 0..7 within wave's 8 rows
  const int scolq = (l & 7) ^ srow;              // inverse-swizzled 16B chunk
  const int pbase = wv * 576 + q * 36;
  const char* kb0 = (const char*)&Kbuf[0][0];
  const char* kb1 = (const char*)&Kbuf[1][0];
  const char* vb0 = (const char*)&Vbuf[0][0];
  const char* vb1 = (const char*)&Vbuf[1][0];
  const int rsw = (q & 7) << 4;                  // read swizzle (byte)

  // per-thread global staging pointers; a 128-col group = 128 K-rows / cols
  const u16* kg = Kp + (size_t)(z * 1024 + wv * 8 + srow) * 64 + scolq * 8;
  const u16* vg = Vp + (size_t)(wv * 8 + srow) * 2048 + z * 1024 + scolq * 8;

  // prologue: stage group 0 (both halves) through regs
  {
    short8 k0 = *(const short8*)kg;
    short8 k1 = *(const short8*)(kg + 4096);
    short8 v0 = *(const short8*)vg;
    short8 v1 = *(const short8*)(vg + 64);
    *(short8*)&Kbuf[0][wv * 512 + l * 8] = k0;
    *(short8*)&Kbuf[1][wv * 512 + l * 8] = k1;
    *(short8*)&Vbuf[0][wv * 512 + l * 8] = v0;
    *(short8*)&Vbuf[1][wv * 512 + l * 8] = v1;
  }
  kg += 8192;
  vg += 128;
  __syncthreads();

  for (int tt = 0; tt < 8; ++tt) {
    // ---- T14 issue-early: next group's loads go in flight NOW
    short8 kr0, kr1, vr0, vr1;
    if (tt < 7) {
      kr0 = *(const short8*)kg;
      kr1 = *(const short8*)(kg + 4096);
      vr0 = *(const short8*)vg;
      vr1 = *(const short8*)(vg + 64);
      kg += 8192;
      vg += 128;
    }

    // ---- S = K . Q' for both halves: sh[h][nj] holds k = h*64+nj*16+4g+r
    f32x4 s0[4], s1[4];
#pragma unroll
    for (int nj = 0; nj < 4; ++nj) {
      s0[nj] = (f32x4){0.f, 0.f, 0.f, 0.f};
      s1[nj] = (f32x4){0.f, 0.f, 0.f, 0.f};
    }
#pragma unroll
    for (int ks = 0; ks < 2; ++ks) {
#pragma unroll
      for (int nj = 0; nj < 4; ++nj) {
        const int off = (nj * 16 + q) * 128 + (((ks * 4 + g) << 4) ^ rsw);
        bf16x8 kf0 = *(const bf16x8*)(kb0 + off);
        bf16x8 kf1 = *(const bf16x8*)(kb1 + off);
        s0[nj] = mfma16(kf0, qf[ks], s0[nj]);
        s1[nj] = mfma16(kf1, qf[ks], s1[nj]);
      }
    }

    // ---- one online-softmax pass over all 32 values (row q, 4 lanes)
    float mt = s0[0][0];
#pragma unroll
    for (int nj = 0; nj < 4; ++nj)
#pragma unroll
      for (int r = 0; r < 4; ++r) {
        mt = fmaxf(mt, s0[nj][r]);
        mt = fmaxf(mt, s1[nj][r]);
      }
    mt = fmaxf(mt, __shfl_xor(mt, 16));
    mt = fmaxf(mt, __shfl_xor(mt, 32));
    if (!__all(mt <= m + 8.f)) {               // defer-max: rescale rarely
      const float nm = fmaxf(m, mt);
      const float rf = fexp2(m - nm);
      m = nm;
      ls *= rf;
#pragma unroll
      for (int df = 0; df < 4; ++df) o_acc[df] *= rf;
    }
    float ps = 0.f;
#pragma unroll
    for (int nj = 0; nj < 4; ++nj)
#pragma unroll
      for (int r = 0; r < 4; ++r) {
        s0[nj][r] = fexp2(s0[nj][r] - m);
        s1[nj][r] = fexp2(s1[nj][r] - m);
        ps += s0[nj][r] + s1[nj][r];
      }
    ps += __shfl_xor(ps, 16);
    ps += __shfl_xor(ps, 32);
    ls += ps;

    // ---- half 0: P -> LDS, then PV (same-wave slab, in-order DS)
#pragma unroll
    for (int nj = 0; nj < 4; ++nj)
#pragma unroll
      for (int pp = 0; pp < 2; ++pp)
        Pl[pbase + nj * 8 + g * 2 + pp] =
            cvt_pk_bf16(s0[nj][2 * pp], s0[nj][2 * pp + 1]);
#pragma unroll
    for (int ks = 0; ks < 2; ++ks) {
      u32x4 pw = *(const u32x4*)&Pl[pbase + ks * 16 + 4 * g];
      bf16x8 pf = __builtin_bit_cast(bf16x8, pw);
#pragma unroll
      for (int df = 0; df < 4; ++df) {
        bf16x8 vf = *(const bf16x8*)(vb0 + (df * 16 + q) * 128 +
                                     (((ks * 4 + g) << 4) ^ rsw));
        o_acc[df] = mfma16(vf, pf, o_acc[df]);
      }
    }

    // ---- half 1: P -> LDS (same addresses; true dep keeps order), then PV
#pragma unroll
    for (int nj = 0; nj < 4; ++nj)
#pragma unroll
      for (int pp = 0; pp < 2; ++pp)
        Pl[pbase + nj * 8 + g * 2 + pp] =
            cvt_pk_bf16(s1[nj][2 * pp], s1[nj][2 * pp + 1]);
#pragma unroll
    for (int ks = 0; ks < 2; ++ks) {
      u32x4 pw = *(const u32x4*)&Pl[pbase + ks * 16 + 4 * g];
      bf16x8 pf = __builtin_bit_cast(bf16x8, pw);
#pragma unroll
      for (int df = 0; df < 4; ++df) {
        bf16x8 vf = *(const bf16x8*)(vb1 + (df * 16 + q) * 128 +
                                     (((ks * 4 + g) << 4) ^ rsw));
        o_acc[df] = mfma16(vf, pf, o_acc[df]);
      }
    }

    // ---- v5 write-late slot: all waves done reading K/V LDS, then overwrite
    __syncthreads();
    if (tt < 7) {
      *(short8*)&Kbuf[0][wv * 512 + l * 8] = kr0;
      *(short8*)&Kbuf[1][wv * 512 + l * 8] = kr1;
      *(short8*)&Vbuf[0][wv * 512 + l * 8] = vr0;
      *(short8*)&Vbuf[1][wv * 512 + l * 8] = vr1;
    }
    __syncthreads();
  }

  // ---- epilogue: write NORMALIZED partial O (bf16) + (m, ls) per row
  const float inv = 1.f / ls;
  const int rowb = qt * 128 + wv * 16 + q;
  const size_t prow = (size_t)(z * 32 + bh) * 2048 + rowb;
  u16* Po = Op + (prow << 6);
#pragma unroll
  for (int df = 0; df < 4; ++df)
#pragma unroll
    for (int pp = 0; pp < 2; ++pp) {
      uint32_t w = cvt_pk_bf16(o_acc[df][2 * pp] * inv,
                               o_acc[df][2 * pp + 1] * inv);
      *(uint32_t*)(Po + df * 16 + 4 * g + 2 * pp) = w;
    }
  if (g == 0) ml[prow] = make_float2(m, ls);
}

// ---------------------------------------------------------------------------
// Combine the two KV-half partials: O = (w1*O1n + w2*O2n), w_i ~ ls_i*2^m_i.
// ---------------------------------------------------------------------------
__global__ __launch_bounds__(256) void combine(
    const uint32_t* __restrict__ Op32, const float2* __restrict__ ml,
    u16* __restrict__ AO) {
  const int j = blockIdx.x * 256 + threadIdx.x;   // [0, 2M)
  const int rowid = j >> 5, w5 = j & 31;
  const float2 a = ml[rowid];
  const float2 c = ml[(1 << 16) + rowid];
  const float M = fmaxf(a.x, c.x);
  float w1 = a.y * fexp2(a.x - M);
  float w2 = c.y * fexp2(c.x - M);
  const float inv = 1.f / (w1 + w2);
  w1 *= inv;
  w2 *= inv;
  const uint32_t p1 = Op32[j];
  const uint32_t p2 = Op32[(1u << 21) + j];
  const float lo = w1 * __builtin_bit_cast(float, p1 << 16) +
                   w2 * __builtin_bit_cast(float, p2 << 16);
  const float hi = w1 * __builtin_bit_cast(float, p1 & 0xffff0000u) +
                   w2 * __builtin_bit_cast(float, p2 & 0xffff0000u);
  const uint32_t outw = cvt_pk_bf16(lo, hi);
  const int bh = rowid >> 11, s = rowid & 2047, b = bh >> 4, h = bh & 15;
  ((uint32_t*)AO)[((size_t)(b * 2048 + s) << 9) + h * 32 + w5] = outw;
}

// ---------------------------------------------------------------------------
extern "C" void kernel_launch(void* const* d_in, const int* in_sizes, int n_in,
                              void* d_out, int out_size, void* d_ws,
                              size_t ws_size, hipStream_t stream) {
  const float* q = (const float*)d_in[0];
  const float* k = (const float*)d_in[1];
  const float* v = (const float*)d_in[2];
  const float* w_q = (const float*)d_in[3];
  const float* b_q = (const float*)d_in[4];
  const float* w_k = (const float*)d_in[5];
  const float* b_k = (const float*)d_in[6];
  const float* w_v = (const float*)d_in[7];
  const float* b_v = (const float*)d_in[8];
  const float* w_o = (const float*)d_in[9];
  const float* b_o = (const float*)d_in[10];

  // ws layout (u16 elems): [0,12M) q/k/v bf16 (DEAD after gemm_proj; reused
  // as flash partials Op[0,8M) + ml at 8M), [12M,16M) weights bf16,
  // [16M,20M) Qh, [20M,24M) Kh, [24M,28M) V^T, [28M,32M) attn out. 64 MB.
  u16* ws = (u16*)d_ws;
  u16* qb = ws;                       // + z*4M for k,v
  u16* wqb = ws + (12u << 20);        // + z*1M for wk,wv (contiguous concat)
  u16* wob = ws + (15u << 20);
  u16* Qh = ws + (16u << 20);         // z=0 (pre-scaled by 0.125*log2e)
  u16* Kh = ws + (20u << 20);         // z=1
  u16* VT = ws + (24u << 20);         // z=2 (transposed)
  u16* AO = ws + (28u << 20);
  u16* Op = ws;                            // bytes [0,16MB): 2 x 4M bf16
  float2* ml = (float2*)(ws + (8u << 20)); // bytes [16,17MB): 128K float2

  cvt_all<<<dim3(8192), dim3(256), 0, stream>>>(q, k, v, w_q, w_k, w_v, w_o, ws);
  gemm_proj<<<dim3(768), dim3(256), 0, stream>>>(qb, wqb, b_q, b_k, b_v, Qh);
  flash_attn7<<<dim3(16, 32, 2), dim3(512), 0, stream>>>(Qh, Kh, VT, Op, ml);
  combine<<<dim3(8192), dim3(256), 0, stream>>>((const uint32_t*)Op, ml, AO);
  gemm_out<<<dim3(512), dim3(512), 0, stream>>>(AO, wob, b_o, (float*)d_out);
}

// Round 26
// 140.553 us; speedup vs baseline: 1.1464x; 1.1464x over previous
//
#include <hip/hip_runtime.h>
#include <hip/hip_bf16.h>
#include <stdint.h>

// Problem constants: B=2, S=2048, D_MODEL=1024, H=16, Dk=64. M = B*S = 4096.
typedef unsigned short u16;
typedef __attribute__((ext_vector_type(8))) short short8;
typedef __attribute__((ext_vector_type(8))) __bf16 bf16x8;
typedef __attribute__((ext_vector_type(4))) float f32x4;
typedef __attribute__((ext_vector_type(4))) uint32_t u32x4;

#if defined(__has_builtin)
#if __has_builtin(__builtin_amdgcn_global_load_lds)
#define USE_GLLDS 1
#endif
#endif

// Fast 2^x: v_exp_f32 is the native HW op. (__exp2f collides with glibc.)
#if defined(__has_builtin)
#if __has_builtin(__builtin_amdgcn_exp2f)
#define HAVE_EXP2_BUILTIN 1
#endif
#endif
__device__ __forceinline__ float fexp2(float x) {
#ifdef HAVE_EXP2_BUILTIN
  return __builtin_amdgcn_exp2f(x);
#else
  return exp2f(x);
#endif
}

__device__ __forceinline__ u16 f2bf(float f) {
  __hip_bfloat16 h = __float2bfloat16(f);
  return __builtin_bit_cast(u16, h);
}

// Pack 2 fp32 -> 1 u32 of 2 bf16 (RNE) in ONE instruction (T12 recipe).
__device__ __forceinline__ uint32_t cvt_pk_bf16(float lo, float hi) {
  uint32_t w;
  asm("v_cvt_pk_bf16_f32 %0, %1, %2" : "=v"(w) : "v"(lo), "v"(hi));
  return w;
}

__device__ __forceinline__ f32x4 mfma16(bf16x8 a, bf16x8 b, f32x4 c) {
  return __builtin_amdgcn_mfma_f32_16x16x32_bf16(a, b, c, 0, 0, 0);
}

#ifdef USE_GLLDS
__device__ __forceinline__ void async_cp16(const void* g, void* l) {
  __builtin_amdgcn_global_load_lds(
      (const __attribute__((address_space(1))) void*)g,
      (__attribute__((address_space(3))) void*)l, 16, 0, 0);
}
#endif

// Shared epilogue for all GEMM variants. Modes:
//   0: Q  -> bf16 split-head [B,H,S,64], scaled by 0.125*log2(e)  (exp2 dom.)
//   1: K  -> bf16 split-head [B,H,S,64]
//   2: V  -> bf16 TRANSPOSED split-head [B,H,64,S]  (V^T for the PV mfma)
//   3: fp32 row-major [4096,1024] (output projection)
__device__ __forceinline__ void gemm_store(float val, int gm, int gn, int mode,
                                           void* __restrict__ outp) {
  const int b = gm >> 11, s = gm & 2047, h = gn >> 6, d = gn & 63;
  if (mode == 3) {
    ((float*)outp)[(size_t)gm * 1024 + gn] = val;
  } else if (mode == 2) {
    ((u16*)outp)[(((size_t)((b * 16 + h) * 64 + d)) << 11) + s] = f2bf(val);
  } else {
    if (mode == 0) val *= 0.18033688f;  // (1/8)*log2(e): exp2-domain
    ((u16*)outp)[(((size_t)((b * 16 + h) * 2048 + s)) << 6) + d] = f2bf(val);
  }
}

// ---------------------------------------------------------------------------
// Kernel 1: fp32 -> bf16 conversion of q,k,v (4M each) and w_q,w_k,w_v,w_o (1M
// each) into one contiguous 16M-element bf16 region at the start of d_ws.
// ---------------------------------------------------------------------------
__global__ __launch_bounds__(256) void cvt_all(
    const float* __restrict__ q, const float* __restrict__ k,
    const float* __restrict__ v, const float* __restrict__ w0,
    const float* __restrict__ w1, const float* __restrict__ w2,
    const float* __restrict__ w3, u16* __restrict__ dst) {
  size_t i = ((size_t)blockIdx.x * 256 + threadIdx.x) * 8;
  const size_t M1 = 1u << 20;
  const float* s;
  size_t base;
  if (i < 4 * M1) { s = q; base = 0; }
  else if (i < 8 * M1) { s = k; base = 4 * M1; }
  else if (i < 12 * M1) { s = v; base = 8 * M1; }
  else if (i < 13 * M1) { s = w0; base = 12 * M1; }
  else if (i < 14 * M1) { s = w1; base = 13 * M1; }
  else if (i < 15 * M1) { s = w2; base = 14 * M1; }
  else { s = w3; base = 15 * M1; }
  const float4 a = *(const float4*)(s + (i - base));
  const float4 b = *(const float4*)(s + (i - base) + 4);
  short8 r;
  r[0] = (short)f2bf(a.x); r[1] = (short)f2bf(a.y);
  r[2] = (short)f2bf(a.z); r[3] = (short)f2bf(a.w);
  r[4] = (short)f2bf(b.x); r[5] = (short)f2bf(b.y);
  r[6] = (short)f2bf(b.z); r[7] = (short)f2bf(b.w);
  *(short8*)(dst + i) = r;
}

// ---------------------------------------------------------------------------
// GEMM core v7 (m97-exact geometry + T2 swizzle): 4 waves (256 thr), 128x128
// tile, BK=64, single 32KB LDS, GLLDS staging. Wave grid 2x2, wave tile
// 64x64, acc 4x4. launch_bounds(256,4) — (256,5) spills acc to scratch
// (round 25: VGPR 48, WRITE_SIZE 124MB, 80us). Do not tighten.
// ---------------------------------------------------------------------------
__device__ __forceinline__ void gemm_core4(const u16* __restrict__ X,
                                           const u16* __restrict__ W,
                                           const float* __restrict__ bias,
                                           void* __restrict__ outp, int mode,
                                           int m0, int n0) {
  __shared__ u16 Al[128 * 64];
  __shared__ u16 Bl[128 * 64];
  const int tid = threadIdx.x;
  const int wv = tid >> 6, l = tid & 63;
  const int wr = wv >> 1, wc = wv & 1;       // wave tile: rows wr*64, cols wc*64
  const int lrow = l & 15, g = l >> 4;
  const int rswe = (lrow & 7) << 3;          // read swizzle (u16 elements)

  f32x4 acc[4][4];
#pragma unroll
  for (int i = 0; i < 4; ++i)
#pragma unroll
    for (int j = 0; j < 4; ++j) acc[i][j] = (f32x4){0.f, 0.f, 0.f, 0.f};

  const int srow = l >> 3;                   // 0..7 (== row&7 for all p)
  const int ccol = l & 7;                    // linear 16B chunk (LDS dest)
  const int gchunk = ccol ^ srow;            // inverse-swizzled source chunk
  const u16* Asrc = X + (size_t)(m0 + wv * 8 + srow) * 1024 + gchunk * 8;
  const u16* Bsrc = W + (size_t)(wv * 8 + srow) * 1024 + gchunk * 8;

  for (int kt = 0; kt < 1024; kt += 64) {
#ifdef USE_GLLDS
#pragma unroll
    for (int p = 0; p < 4; ++p) {
      async_cp16(Asrc + (size_t)p * 32 * 1024 + kt, &Al[p * 2048 + wv * 512]);
      async_cp16(Bsrc + (size_t)p * 32 * 1024 + kt, &Bl[p * 2048 + wv * 512]);
    }
#else
    short8 ar[4], br[4];
#pragma unroll
    for (int p = 0; p < 4; ++p) {
      ar[p] = *(const short8*)(Asrc + (size_t)p * 32 * 1024 + kt);
      br[p] = *(const short8*)(Bsrc + (size_t)p * 32 * 1024 + kt);
    }
#pragma unroll
    for (int p = 0; p < 4; ++p) {
      *(short8*)&Al[(p * 32 + wv * 8 + srow) * 64 + ccol * 8] = ar[p];
      *(short8*)&Bl[(p * 32 + wv * 8 + srow) * 64 + ccol * 8] = br[p];
    }
#endif
    __syncthreads();   // drains staging
#pragma unroll
    for (int ks = 0; ks < 2; ++ks) {
      bf16x8 af[4], bf[4];
      const int qoff = (((ks * 4 + g) << 3) ^ rswe);  // swizzled quad offset
#pragma unroll
      for (int mf = 0; mf < 4; ++mf)
        af[mf] = *(const bf16x8*)&Al[(wr * 64 + mf * 16 + lrow) * 64 + qoff];
#pragma unroll
      for (int nf = 0; nf < 4; ++nf)
        bf[nf] = *(const bf16x8*)&Bl[(wc * 64 + nf * 16 + lrow) * 64 + qoff];
#pragma unroll
      for (int mf = 0; mf < 4; ++mf)
#pragma unroll
        for (int nf = 0; nf < 4; ++nf)
          acc[mf][nf] = mfma16(af[mf], bf[nf], acc[mf][nf]);
    }
    __syncthreads();   // protect buffer before next stage overwrites
  }

  const int rb = (l >> 4) * 4;
#pragma unroll
  for (int mf = 0; mf < 4; ++mf)
#pragma unroll
    for (int nf = 0; nf < 4; ++nf) {
      const int gn = n0 + wc * 64 + nf * 16 + lrow;
      const float bi = bias[gn];
#pragma unroll
      for (int r = 0; r < 4; ++r) {
        const int gm = m0 + wr * 64 + mf * 16 + rb + r;
        gemm_store(acc[mf][nf][r] + bi, gm, gn, mode, outp);
      }
    }
}

// 8-wave BN=64 core (round-18 proven) -- kept for gemm_out.
__device__ __forceinline__ void gemm_core8_64(const u16* __restrict__ X,
                                              const u16* __restrict__ W,
                                              const float* __restrict__ bias,
                                              void* __restrict__ outp,
                                              int mode, int m0, int n0) {
  __shared__ u16 Al[128 * 64];
  __shared__ u16 Bl[64 * 64];
  const int tid = threadIdx.x;
  const int wv = tid >> 6, l = tid & 63;
  const int wr = wv >> 2, wc = wv & 3;       // wave: rows wr*64, cols wc*16
  const int lrow = l & 15, g = l >> 4;
  const int rswe = (lrow & 7) << 3;

  f32x4 acc[4];
#pragma unroll
  for (int i = 0; i < 4; ++i) acc[i] = (f32x4){0.f, 0.f, 0.f, 0.f};

  const int srow = l >> 3;
  const int ccol = l & 7;
  const int gchunk = ccol ^ srow;
  const int arow = wv * 8 + srow;
  const u16* Asrc = X + (size_t)(m0 + arow) * 1024 + gchunk * 8;
  const u16* Bsrc = W + (size_t)arow * 1024 + gchunk * 8;

  for (int kt = 0; kt < 1024; kt += 64) {
#ifdef USE_GLLDS
    async_cp16(Asrc + kt, &Al[(wv * 8) * 64]);
    async_cp16(Asrc + (size_t)64 * 1024 + kt, &Al[(wv * 8 + 64) * 64]);
    async_cp16(Bsrc + kt, &Bl[(wv * 8) * 64]);
#else
    short8 a0 = *(const short8*)(Asrc + kt);
    short8 a1 = *(const short8*)(Asrc + (size_t)64 * 1024 + kt);
    short8 b0 = *(const short8*)(Bsrc + kt);
    *(short8*)&Al[arow * 64 + ccol * 8] = a0;
    *(short8*)&Al[(arow + 64) * 64 + ccol * 8] = a1;
    *(short8*)&Bl[arow * 64 + ccol * 8] = b0;
#endif
    __syncthreads();
#pragma unroll
    for (int ks = 0; ks < 2; ++ks) {
      bf16x8 af[4], bf;
      const int qoff = (((ks * 4 + g) << 3) ^ rswe);
#pragma unroll
      for (int mf = 0; mf < 4; ++mf)
        af[mf] = *(const bf16x8*)&Al[(wr * 64 + mf * 16 + lrow) * 64 + qoff];
      bf = *(const bf16x8*)&Bl[(wc * 16 + lrow) * 64 + qoff];
#pragma unroll
      for (int mf = 0; mf < 4; ++mf) acc[mf] = mfma16(af[mf], bf, acc[mf]);
    }
    __syncthreads();
  }

  const int rb = (l >> 4) * 4;
#pragma unroll
  for (int mf = 0; mf < 4; ++mf) {
    const int gn = n0 + wc * 16 + lrow;
    const float bi = bias[gn];
#pragma unroll
    for (int r = 0; r < 4; ++r) {
      const int gm = m0 + wr * 64 + mf * 16 + rb + r;
      gemm_store(acc[mf][r] + bi, gm, gn, mode, outp);
    }
  }
}

// gemm_proj: 4-wave m97-shape core. Fused grid over concatenated-N (N=3072).
// 768 blocks; XCD-chunk swizzle: chunk = 96 blocks (12 nx x 8 my).
__global__ __launch_bounds__(256, 4) void gemm_proj(
    const u16* __restrict__ qb, const u16* __restrict__ wqb,
    const float* __restrict__ b_q, const float* __restrict__ b_k,
    const float* __restrict__ b_v, u16* __restrict__ Qh) {
  const int s = blockIdx.x;
  const int xcd = s & 7, c = s >> 3;              // c in [0,96)
  const int nx = (xcd >> 2) * 12 + (c % 12);      // [0,24)
  const int my = (xcd & 3) * 8 + (c / 12);        // [0,32)
  const int z = nx >> 3, nxl = nx & 7;
  const float* bias = (z == 0) ? b_q : ((z == 1) ? b_k : b_v);
  gemm_core4(qb + ((size_t)z << 22), wqb + ((size_t)nx << 17), bias,
             Qh + ((size_t)z << 22), z, my * 128, nxl * 128);
}

// gemm_out: BN=64 tile -> 512 blocks (2 blocks/CU). Chunk = 64 (8 nx x 8 my).
__global__ __launch_bounds__(512, 6) void gemm_out(
    const u16* __restrict__ X, const u16* __restrict__ W,
    const float* __restrict__ bias, float* __restrict__ out) {
  const int s = blockIdx.x;
  const int xcd = s & 7, c = s >> 3;              // c in [0,64)
  const int nx = (xcd >> 2) * 8 + (c & 7);        // [0,16)
  const int my = (xcd & 3) * 8 + (c >> 3);        // [0,32)
  gemm_core8_64(X, W + ((size_t)nx << 16), bias, out, 3, my * 128, nx * 64);
}

// ---------------------------------------------------------------------------
// Flash attention v7 EXACT (best measured: 57.4-58.5us, rounds 13/14/20/21/24).
// v5 sync structure (2 barriers per staging slot, T14 issue-early/write-late),
// KVBLK=128, XOR-swizzled K/V, split-KV(2), separate Pl slab, NO setprio.
// ---------------------------------------------------------------------------
__global__ __launch_bounds__(512, 4) void flash_attn7(
    const u16* __restrict__ Qh, const u16* __restrict__ Kh,
    const u16* __restrict__ VT, u16* __restrict__ Op,
    float2* __restrict__ ml) {
  __shared__ __align__(16) u16 Kbuf[2][4096];    // halves 0,1 of 128-col group
  __shared__ __align__(16) u16 Vbuf[2][4096];
  __shared__ __align__(16) uint32_t Pl[8 * 576]; // per-wave 16 rows x 36 dw

  const int tid = threadIdx.x;
  const int wv = tid >> 6, l = tid & 63;
  const int q = l & 15, g = l >> 4;

  // XCD swizzle: dispatch slot s -> original block o = (s%8)*128 + s/8.
  const int s_lin = blockIdx.x + (blockIdx.y << 4) + (blockIdx.z << 9);
  const int o = ((s_lin & 7) << 7) + (s_lin >> 3);
  const int qt = o & 15, bh = (o >> 4) & 31, z = o >> 9;

  const u16* Qp = Qh + ((size_t)bh * 2048 + qt * 128 + wv * 16) * 64;
  const u16* Kp = Kh + (size_t)bh * 2048 * 64;
  const u16* Vp = VT + (size_t)bh * 64 * 2048;

  // Q fragments (B-operand): lane holds Q[q=l&15][d = ks*32 + g*8 .. +7]
  bf16x8 qf[2];
  qf[0] = *(const bf16x8*)(Qp + q * 64 + g * 8);
  qf[1] = *(const bf16x8*)(Qp + q * 64 + 32 + g * 8);

  f32x4 o_acc[4];
#pragma unroll
  for (int df = 0; df < 4; ++df) o_acc[df] = (f32x4){0.f, 0.f, 0.f, 0.f};
  float m = -1e30f, ls = 0.f;

  const int srow = l >> 3;                       // 0..7 within wave's 8 rows
  const int scolq = (l & 7) ^ srow;              // inverse-swizzled 16B chunk
  const int pbase = wv * 576 + q * 36;
  const char* kb0 = (const char*)&Kbuf[0][0];
  const char* kb1 = (const char*)&Kbuf[1][0];
  const char* vb0 = (const char*)&Vbuf[0][0];
  const char* vb1 = (const char*)&Vbuf[1][0];
  const int rsw = (q & 7) << 4;                  // read swizzle (byte)

  // per-thread global staging pointers; a 128-col group = 128 K-rows / cols
  const u16* kg = Kp + (size_t)(z * 1024 + wv * 8 + srow) * 64 + scolq * 8;
  const u16* vg = Vp + (size_t)(wv * 8 + srow) * 2048 + z * 1024 + scolq * 8;

  // prologue: stage group 0 (both halves) through regs
  {
    short8 k0 = *(const short8*)kg;
    short8 k1 = *(const short8*)(kg + 4096);
    short8 v0 = *(const short8*)vg;
    short8 v1 = *(const short8*)(vg + 64);
    *(short8*)&Kbuf[0][wv * 512 + l * 8] = k0;
    *(short8*)&Kbuf[1][wv * 512 + l * 8] = k1;
    *(short8*)&Vbuf[0][wv * 512 + l * 8] = v0;
    *(short8*)&Vbuf[1][wv * 512 + l * 8] = v1;
  }
  kg += 8192;
  vg += 128;
  __syncthreads();

  for (int tt = 0; tt < 8; ++tt) {
    // ---- T14 issue-early: next group's loads go in flight NOW
    short8 kr0, kr1, vr0, vr1;
    if (tt < 7) {
      kr0 = *(const short8*)kg;
      kr1 = *(const short8*)(kg + 4096);
      vr0 = *(const short8*)vg;
      vr1 = *(const short8*)(vg + 64);
      kg += 8192;
      vg += 128;
    }

    // ---- S = K . Q' for both halves: sh[h][nj] holds k = h*64+nj*16+4g+r
    f32x4 s0[4], s1[4];
#pragma unroll
    for (int nj = 0; nj < 4; ++nj) {
      s0[nj] = (f32x4){0.f, 0.f, 0.f, 0.f};
      s1[nj] = (f32x4){0.f, 0.f, 0.f, 0.f};
    }
#pragma unroll
    for (int ks = 0; ks < 2; ++ks) {
#pragma unroll
      for (int nj = 0; nj < 4; ++nj) {
        const int off = (nj * 16 + q) * 128 + (((ks * 4 + g) << 4) ^ rsw);
        bf16x8 kf0 = *(const bf16x8*)(kb0 + off);
        bf16x8 kf1 = *(const bf16x8*)(kb1 + off);
        s0[nj] = mfma16(kf0, qf[ks], s0[nj]);
        s1[nj] = mfma16(kf1, qf[ks], s1[nj]);
      }
    }

    // ---- one online-softmax pass over all 32 values (row q, 4 lanes)
    float mt = s0[0][0];
#pragma unroll
    for (int nj = 0; nj < 4; ++nj)
#pragma unroll
      for (int r = 0; r < 4; ++r) {
        mt = fmaxf(mt, s0[nj][r]);
        mt = fmaxf(mt, s1[nj][r]);
      }
    mt = fmaxf(mt, __shfl_xor(mt, 16));
    mt = fmaxf(mt, __shfl_xor(mt, 32));
    if (!__all(mt <= m + 8.f)) {               // defer-max: rescale rarely
      const float nm = fmaxf(m, mt);
      const float rf = fexp2(m - nm);
      m = nm;
      ls *= rf;
#pragma unroll
      for (int df = 0; df < 4; ++df) o_acc[df] *= rf;
    }
    float ps = 0.f;
#pragma unroll
    for (int nj = 0; nj < 4; ++nj)
#pragma unroll
      for (int r = 0; r < 4; ++r) {
        s0[nj][r] = fexp2(s0[nj][r] - m);
        s1[nj][r] = fexp2(s1[nj][r] - m);
        ps += s0[nj][r] + s1[nj][r];
      }
    ps += __shfl_xor(ps, 16);
    ps += __shfl_xor(ps, 32);
    ls += ps;

    // ---- half 0: P -> LDS, then PV (same-wave slab, in-order DS)
#pragma unroll
    for (int nj = 0; nj < 4; ++nj)
#pragma unroll
      for (int pp = 0; pp < 2; ++pp)
        Pl[pbase + nj * 8 + g * 2 + pp] =
            cvt_pk_bf16(s0[nj][2 * pp], s0[nj][2 * pp + 1]);
#pragma unroll
    for (int ks = 0; ks < 2; ++ks) {
      u32x4 pw = *(const u32x4*)&Pl[pbase + ks * 16 + 4 * g];
      bf16x8 pf = __builtin_bit_cast(bf16x8, pw);
#pragma unroll
      for (int df = 0; df < 4; ++df) {
        bf16x8 vf = *(const bf16x8*)(vb0 + (df * 16 + q) * 128 +
                                     (((ks * 4 + g) << 4) ^ rsw));
        o_acc[df] = mfma16(vf, pf, o_acc[df]);
      }
    }

    // ---- half 1: P -> LDS (same addresses; true dep keeps order), then PV
#pragma unroll
    for (int nj = 0; nj < 4; ++nj)
#pragma unroll
      for (int pp = 0; pp < 2; ++pp)
        Pl[pbase + nj * 8 + g * 2 + pp] =
            cvt_pk_bf16(s1[nj][2 * pp], s1[nj][2 * pp + 1]);
#pragma unroll
    for (int ks = 0; ks < 2; ++ks) {
      u32x4 pw = *(const u32x4*)&Pl[pbase + ks * 16 + 4 * g];
      bf16x8 pf = __builtin_bit_cast(bf16x8, pw);
#pragma unroll
      for (int df = 0; df < 4; ++df) {
        bf16x8 vf = *(const bf16x8*)(vb1 + (df * 16 + q) * 128 +
                                     (((ks * 4 + g) << 4) ^ rsw));
        o_acc[df] = mfma16(vf, pf, o_acc[df]);
      }
    }

    // ---- v5 write-late slot: all waves done reading K/V LDS, then overwrite
    __syncthreads();
    if (tt < 7) {
      *(short8*)&Kbuf[0][wv * 512 + l * 8] = kr0;
      *(short8*)&Kbuf[1][wv * 512 + l * 8] = kr1;
      *(short8*)&Vbuf[0][wv * 512 + l * 8] = vr0;
      *(short8*)&Vbuf[1][wv * 512 + l * 8] = vr1;
    }
    __syncthreads();
  }

  // ---- epilogue: write NORMALIZED partial O (bf16) + (m, ls) per row
  const float inv = 1.f / ls;
  const int rowb = qt * 128 + wv * 16 + q;
  const size_t prow = (size_t)(z * 32 + bh) * 2048 + rowb;
  u16* Po = Op + (prow << 6);
#pragma unroll
  for (int df = 0; df < 4; ++df)
#pragma unroll
    for (int pp = 0; pp < 2; ++pp) {
      uint32_t w = cvt_pk_bf16(o_acc[df][2 * pp] * inv,
                               o_acc[df][2 * pp + 1] * inv);
      *(uint32_t*)(Po + df * 16 + 4 * g + 2 * pp) = w;
    }
  if (g == 0) ml[prow] = make_float2(m, ls);
}

// ---------------------------------------------------------------------------
// Combine the two KV-half partials: O = (w1*O1n + w2*O2n), w_i ~ ls_i*2^m_i.
// ---------------------------------------------------------------------------
__global__ __launch_bounds__(256) void combine(
    const uint32_t* __restrict__ Op32, const float2* __restrict__ ml,
    u16* __restrict__ AO) {
  const int j = blockIdx.x * 256 + threadIdx.x;   // [0, 2M)
  const int rowid = j >> 5, w5 = j & 31;
  const float2 a = ml[rowid];
  const float2 c = ml[(1 << 16) + rowid];
  const float M = fmaxf(a.x, c.x);
  float w1 = a.y * fexp2(a.x - M);
  float w2 = c.y * fexp2(c.x - M);
  const float inv = 1.f / (w1 + w2);
  w1 *= inv;
  w2 *= inv;
  const uint32_t p1 = Op32[j];
  const uint32_t p2 = Op32[(1u << 21) + j];
  const float lo = w1 * __builtin_bit_cast(float, p1 << 16) +
                   w2 * __builtin_bit_cast(float, p2 << 16);
  const float hi = w1 * __builtin_bit_cast(float, p1 & 0xffff0000u) +
                   w2 * __builtin_bit_cast(float, p2 & 0xffff0000u);
  const uint32_t outw = cvt_pk_bf16(lo, hi);
  const int bh = rowid >> 11, s = rowid & 2047, b = bh >> 4, h = bh & 15;
  ((uint32_t*)AO)[((size_t)(b * 2048 + s) << 9) + h * 32 + w5] = outw;
}

// ---------------------------------------------------------------------------
extern "C" void kernel_launch(void* const* d_in, const int* in_sizes, int n_in,
                              void* d_out, int out_size, void* d_ws,
                              size_t ws_size, hipStream_t stream) {
  const float* q = (const float*)d_in[0];
  const float* k = (const float*)d_in[1];
  const float* v = (const float*)d_in[2];
  const float* w_q = (const float*)d_in[3];
  const float* b_q = (const float*)d_in[4];
  const float* w_k = (const float*)d_in[5];
  const float* b_k = (const float*)d_in[6];
  const float* w_v = (const float*)d_in[7];
  const float* b_v = (const float*)d_in[8];
  const float* w_o = (const float*)d_in[9];
  const float* b_o = (const float*)d_in[10];

  // ws layout (u16 elems): [0,12M) q/k/v bf16 (DEAD after gemm_proj; reused
  // as flash partials Op[0,8M) + ml at 8M), [12M,16M) weights bf16,
  // [16M,20M) Qh, [20M,24M) Kh, [24M,28M) V^T, [28M,32M) attn out. 64 MB.
  u16* ws = (u16*)d_ws;
  u16* qb = ws;                       // + z*4M for k,v
  u16* wqb = ws + (12u << 20);        // + z*1M for wk,wv (contiguous concat)
  u16* wob = ws + (15u << 20);
  u16* Qh = ws + (16u << 20);         // z=0 (pre-scaled by 0.125*log2e)
  u16* Kh = ws + (20u << 20);         // z=1
  u16* VT = ws + (24u << 20);         // z=2 (transposed)
  u16* AO = ws + (28u << 20);
  u16* Op = ws;                            // bytes [0,16MB): 2 x 4M bf16
  float2* ml = (float2*)(ws + (8u << 20)); // bytes [16,17MB): 128K float2

  cvt_all<<<dim3(8192), dim3(256), 0, stream>>>(q, k, v, w_q, w_k, w_v, w_o, ws);
  gemm_proj<<<dim3(768), dim3(256), 0, stream>>>(qb, wqb, b_q, b_k, b_v, Qh);
  flash_attn7<<<dim3(16, 32, 2), dim3(512), 0, stream>>>(Qh, Kh, VT, Op, ml);
  combine<<<dim3(8192), dim3(256), 0, stream>>>((const uint32_t*)Op, ml, AO);
  gemm_out<<<dim3(512), dim3(512), 0, stream>>>(AO, wob, b_o, (float*)d_out);
}